// Round 7
// baseline (1006.467 us; speedup 1.0000x reference)
//
#include <hip/hip_runtime.h>
#include <hip/hip_bf16.h>

#define NBATCH 2
#define NBB    16
#define NIC    8
#define NOC    16
#define NQ     30
#define NMM    6
#define NU     5
#define NV     5
#define NNC    25   // NU*NV

// ---- hand-unrolled basis + tap macros: NO private arrays anywhere ----
#define LOADT(u) const float pTre##u = pTau_re[qm * NU + u], pTim##u = pTau_im[qm * NU + u];
#define LOADS(v) const float pSre##v = pPsi_re[m * NV + v],  pSim##v = pPsi_im[m * NV + v];

#define EV(v)                                                 \
    const float rr_##v  = __expf(ps * pSre##v);               \
    const float evr##v  = rr_##v * __cosf(ps * pSim##v);      \
    const float evi##v  = rr_##v * __sinf(ps * pSim##v);

#define TAPV(u, v) {                                          \
    const float tr = gr * evr##v - gi * evi##v;               \
    const float ti = gr * evi##v + gi * evr##v;               \
    const float4 wA = wbase[(u * NV + v) * 8];                \
    const float4 wB = wbase[(u * NV + v) * 8 + 1];            \
    a0r += tr * wA.x - ti * wA.y;  a0i += tr * wA.y + ti * wA.x; \
    a1r += tr * wA.z - ti * wA.w;  a1i += tr * wA.w + ti * wA.z; \
    a2r += tr * wB.x - ti * wB.y;  a2i += tr * wB.y + ti * wB.x; \
    a3r += tr * wB.z - ti * wB.w;  a3i += tr * wB.w + ti * wB.z; }

#define TAPU(u) {                                             \
    const float ru  = __expf(lt * pTre##u);                   \
    const float eur = ru * __cosf(lt * pTim##u);              \
    const float eui = ru * __sinf(lt * pTim##u);              \
    const float gr  = Are * eur - Aim * eui;                  \
    const float gi  = Are * eui + Aim * eur;                  \
    TAPV(u, 0) TAPV(u, 1) TAPV(u, 2) TAPV(u, 3) TAPV(u, 4) }

__global__ __launch_bounds__(256, 2) void lbc_main(
    const float* __restrict__ x_re,   const float* __restrict__ x_im,
    const float* __restrict__ lnAlpha,const float* __restrict__ Phi,
    const float* __restrict__ lnTau,  const float* __restrict__ Psi,
    const float* __restrict__ pAlpha_re, const float* __restrict__ pAlpha_im,
    const float* __restrict__ pPhi_re,   const float* __restrict__ pPhi_im,
    const float* __restrict__ pTau_re,   const float* __restrict__ pTau_im,
    const float* __restrict__ pPsi_re,   const float* __restrict__ pPsi_im,
    const float* __restrict__ F_re,      const float* __restrict__ F_im,
    const float* __restrict__ coeffs,
    float* __restrict__ out)
{
    __shared__ float2 Wp[NIC * NNC * NOC];   // 25.6 KiB

    // Block identity: bid = ((b*NQ + q)*NMM + m)*4 + qt
    const int bid = blockIdx.x;
    const int qt  = bid & 3;
    const int bqm = bid >> 2;
    const int m   = bqm % NMM;
    const int q   = (bqm / NMM) % NQ;
    const int b   = bqm / (NMM * NQ);
    const int qm  = q * NMM + m;

    // ---- Stage W' = collect_weights(coeffs) * F[qm] into LDS ----
    for (int idx = threadIdx.x; idx < NIC * NNC * NOC; idx += 256) {
        const int o = idx & (NOC - 1);
        const int n = (idx >> 4) % NNC;
        const int c = idx / (NOC * NNC);
        float wr, wi;
        if (n < 12) {
            wr = coeffs[(c * NNC + (23 - 2 * n)) * NOC + o];
            wi = coeffs[(c * NNC + (24 - 2 * n)) * NOC + o];
        } else if (n == 12) {
            wr = coeffs[(c * NNC + 0) * NOC + o];
            wi = 0.0f;
        } else {
            wr = coeffs[(c * NNC + (2 * n - 25)) * NOC + o];
            wi = coeffs[(c * NNC + (2 * n - 24)) * NOC + o];
        }
        const float fr = F_re[qm * NNC + n];
        const float fi = F_im[qm * NNC + n];
        Wp[idx] = make_float2(wr * fr - wi * fi, wr * fi + wi * fr);
    }
    __syncthreads();

    // ---- Thread identity: og = o-group (wave-uniform), p = point ----
    const int tid = threadIdx.x;
    const int og  = tid >> 6;                // 0..3
    const int p   = tid & 63;
    const int y   = qt * 4 + (p >> 4);
    const int x   = p & 15;
    const int pbase = ((b * NBB + y) * NBB + x) * NIC;

    // ---- Block-uniform params: uniform addresses -> scalar regs ----
    const float pAre = pAlpha_re[qm], pAim = pAlpha_im[qm];
    const float pPre = pPhi_re[m],    pPim = pPhi_im[m];
    LOADT(0) LOADT(1) LOADT(2) LOADT(3) LOADT(4)
    LOADS(0) LOADS(1) LOADS(2) LOADS(3) LOADS(4)

    // ---- Named scalar accumulators (4 o's per thread) ----
    float a0r = 0.f, a0i = 0.f, a1r = 0.f, a1i = 0.f;
    float a2r = 0.f, a2i = 0.f, a3r = 0.f, a3i = 0.f;

    #pragma unroll 1
    for (int c = 0; c < NIC; ++c) {
        const int pc = pbase + c;
        const float xr = x_re[pc], xi = x_im[pc];
        const float la = lnAlpha[pc], ph = Phi[pc];
        const float lt = lnTau[pc],   ps = Psi[pc];

        // A = x * exp(la*pAlpha + ph*pPhi)
        const float ar = la * pAre + ph * pPre;
        const float ai = la * pAim + ph * pPim;
        const float ea  = __expf(ar);
        const float er_ = ea * __cosf(ai);
        const float ei_ = ea * __sinf(ai);
        const float Are = xr * er_ - xi * ei_;
        const float Aim = xr * ei_ + xi * er_;

        // v-basis as named scalars
        EV(0) EV(1) EV(2) EV(3) EV(4)

        // W' fragment base for this (c, og): float4 pairs per tap
        const float4* wbase = reinterpret_cast<const float4*>(Wp)
                              + c * (NNC * NOC / 2) + og * 2;

        TAPU(0) TAPU(1) TAPU(2) TAPU(3) TAPU(4)
    }

    // ---- Write out: [b, o, q, m, y, x, 2], o = og*4 .. og*4+3 ----
    float2* const o2 = reinterpret_cast<float2*>(out);
    const size_t stride_o = (size_t)NQ * NMM * NBB * NBB;   // 46080
    size_t oi = ((((size_t)b * NOC + og * 4) * NQ + q) * NMM + m) * (NBB * NBB)
                + y * NBB + x;
    o2[oi]                = make_float2(a0r, a0i);
    o2[oi +     stride_o] = make_float2(a1r, a1i);
    o2[oi + 2 * stride_o] = make_float2(a2r, a2i);
    o2[oi + 3 * stride_o] = make_float2(a3r, a3i);
}

extern "C" void kernel_launch(void* const* d_in, const int* in_sizes, int n_in,
                              void* d_out, int out_size, void* d_ws, size_t ws_size,
                              hipStream_t stream) {
    const float* x_re      = (const float*)d_in[0];
    const float* x_im      = (const float*)d_in[1];
    const float* lnAlpha   = (const float*)d_in[2];
    const float* Phi       = (const float*)d_in[3];
    const float* lnTau     = (const float*)d_in[4];
    const float* Psi       = (const float*)d_in[5];
    const float* pAlpha_re = (const float*)d_in[6];
    const float* pAlpha_im = (const float*)d_in[7];
    const float* pPhi_re   = (const float*)d_in[8];
    const float* pPhi_im   = (const float*)d_in[9];
    const float* pTau_re   = (const float*)d_in[10];
    const float* pTau_im   = (const float*)d_in[11];
    const float* pPsi_re   = (const float*)d_in[12];
    const float* pPsi_im   = (const float*)d_in[13];
    const float* F_re      = (const float*)d_in[14];
    const float* F_im      = (const float*)d_in[15];
    const float* coeffs    = (const float*)d_in[16];
    float* out = (float*)d_out;

    dim3 grid(NBATCH * NQ * NMM * 4);   // 1440: (b,q,m) x 4 quarter-tiles
    dim3 block(256);                    // 4 o-group waves x 64 points
    lbc_main<<<grid, block, 0, stream>>>(
        x_re, x_im, lnAlpha, Phi, lnTau, Psi,
        pAlpha_re, pAlpha_im, pPhi_re, pPhi_im,
        pTau_re, pTau_im, pPsi_re, pPsi_im,
        F_re, F_im, coeffs, out);
}